// Round 7
// baseline (244.861 us; speedup 1.0000x reference)
//
#include <hip/hip_runtime.h>
#include <math.h>

#define FIELD  39
#define NPF    38        // fields in the pairwise term (0..37)
#define NPAIRS 703       // C(38,2)
#define FEAT   100000
#define EMB    10

#define CHUNK_B    464   // 38 rows * 12 B (10 fp8 + 2 pad) = 456 -> pad to 464 (29 uint4)
#define CHUNK_U32  116
#define CHUNK_U16B 29
#define ROW_B      12
#define RCOLS      32    // columns per repack block; 100000 = 3125*32 exactly

#define SCALE      512.0f                 // 2^9: centers N(0,0.01) in e4m3 range
#define INV_SCALE2 3.814697265625e-06f    // 2^-18

#define FLAGS_OFF  (48u * 1024u * 1024u)  // flags live past T (46.4 MB) in d_ws

typedef float floatx2 __attribute__((ext_vector_type(2)));
typedef const void __attribute__((address_space(1)))* gas_ptr;
typedef void       __attribute__((address_space(3)))* las_ptr;

// closed-form pair decode: p -> (i,j), 0 <= i < j < 38
__device__ __forceinline__ void decode_pair(int p, int& i_out, int& j_out) {
    const float disc = 5625.0f - 8.0f * (float)p;
    int i = (int)((75.0f - sqrtf(disc)) * 0.5f);
    int off = (i * (75 - i)) >> 1;
    if (p < off) {
        --i; off = (i * (75 - i)) >> 1;
    } else {
        const int off1 = ((i + 1) * (74 - i)) >> 1;
        if (p >= off1) { ++i; off = off1; }
    }
    i_out = i;
    j_out = i + 1 + (p - off);
}

// ---------------------------------------------------------------------------
// Kernel 0: mark used columns. flag semantics: 0 => used; anything else
// (0xAA poison) => unused. Writing 0 is idempotent/race-free; if poison were
// ever absent, false-"used" flags only cost extra repack work, never wrong
// results (idxs are identical each replay).
// ---------------------------------------------------------------------------
__global__ __launch_bounds__(256) void flag_kernel(
    const int* __restrict__ idxs, unsigned char* __restrict__ flags, int nref)
{
    const int g = blockIdx.x * 256 + threadIdx.x;    // over B*38
    if (g >= nref) return;
    const int b = (int)(((unsigned long long)g * 220753ull) >> 23);  // g/38, exact g<1.4M
    const int f = g - b * NPF;
    flags[idxs[b * FIELD + f]] = 0;
}

// ---------------------------------------------------------------------------
// Kernel 1: repack emb [39,100000,10] f32 -> T [100000] x 464B fp8 chunks,
// skipping unused columns (load/convert skip when a float4 spans only
// unused cols; store skip per column).
// ---------------------------------------------------------------------------
__global__ __launch_bounds__(256) void repack_kernel(
    const float4* __restrict__ emb4, uint4* __restrict__ T4,
    const unsigned char* __restrict__ flags)
{
    __shared__ unsigned char sB[RCOLS * CHUNK_B];   // 14,848 B
    __shared__ unsigned char sFlag[RCOLS];
    const int t  = threadIdx.x;
    const int bx = blockIdx.x;
    const float4* __restrict__ base = emb4 + (size_t)80 * bx;

    if (t < RCOLS) sFlag[t] = flags[bx * RCOLS + t];
    __syncthreads();

    // stage 1: 38 slabs x 80 float4 (= 32 cols x 10 f32) = 3040 float4
    #pragma unroll
    for (int g = 0; g < 2; ++g) {
        float4 v[6];
        int    ib[6], e0[6];
        bool   ok[6];
        #pragma unroll
        for (int k = 0; k < 6; ++k) {
            const int u = t + (6 * g + k) * 256;
            const bool inb = (u < NPF * 80);
            const int uc = inb ? u : 0;
            const int i  = (int)(((unsigned)uc * 52429u) >> 22);   // uc/80 exact for uc<3040
            const int q  = uc - i * 80;
            ib[k] = i;
            e0[k] = q << 2;                                        // element in [0,320)
            const int cA = (e0[k] * 6554) >> 16;                   // e/10 exact for e<320
            const int cB = ((e0[k] + 3) * 6554) >> 16;
            ok[k] = inb && ((sFlag[cA] == 0) || (sFlag[cB] == 0));
            v[k] = ok[k] ? base[i * 250000 + q] : float4{0.f, 0.f, 0.f, 0.f};
        }
        #pragma unroll
        for (int k = 0; k < 6; ++k) {
            if (!ok[k]) continue;
            const unsigned lo = __builtin_amdgcn_cvt_pk_fp8_f32(v[k].x * SCALE, v[k].y * SCALE, 0, false);
            const unsigned hi = __builtin_amdgcn_cvt_pk_fp8_f32(v[k].z * SCALE, v[k].w * SCALE, 0, false);
            const int i = ib[k];
            {
                const int e   = e0[k];
                const int col = (e * 6554) >> 16;
                const int off = e - 10 * col;          // even
                *(ushort*)(sB + col * CHUNK_B + i * ROW_B + off) = (ushort)lo;
            }
            {
                const int e   = e0[k] + 2;
                const int col = (e * 6554) >> 16;
                const int off = e - 10 * col;
                *(ushort*)(sB + col * CHUNK_B + i * ROW_B + off) = (ushort)hi;
            }
        }
    }
    __syncthreads();

    // stage 2: contiguous uint4 stores, used columns only
    const uint4* s4 = (const uint4*)sB;
    for (int u = t; u < RCOLS * CHUNK_U16B; u += 256) {
        const int col = (u * 2261) >> 16;              // u/29 exact for u<1102
        if (sFlag[col] == 0)
            T4[(size_t)bx * (RCOLS * CHUNK_U16B) + u] = s4[u];
    }
}

// ---------------------------------------------------------------------------
// Kernel 2: per-batch FFM from the fp8 table; staging via global_load_lds.
// ---------------------------------------------------------------------------
__global__ __launch_bounds__(256) void ffm_kernel(
    const int*   __restrict__ idxs,   // [B, 39]
    const float* __restrict__ vals,   // [B, 39]
    const uint4* __restrict__ T4,     // [FEAT][29] uint4
    const float* __restrict__ w1,     // [100000, 1]
    float*       __restrict__ out)    // [B]
{
    const int b = blockIdx.x;
    const int t = threadIdx.x;

    __shared__ int      s_idx[FIELD];
    __shared__ float    s_val[FIELD];
    __shared__ unsigned sM[NPF * CHUNK_U32];   // 17,632 B

    if (t < FIELD) {
        s_idx[t] = idxs[b * FIELD + t];
        s_val[t] = vals[b * FIELD + t];
    }
    __syncthreads();

    // first-order gather first so it overlaps the staging DMA
    float acc = (t < FIELD) ? w1[s_idx[t]] * s_val[t] : 0.f;

    // stage 38 chunks (464 B each) into LDS: 38*29 = 1102 uint4, async
    {
        uint4* sM4 = (uint4*)sM;
        #pragma unroll
        for (int g = 0; g < 5; ++g) {
            const int u = t + g * 256;
            if (u < NPF * CHUNK_U16B) {
                const int f  = (u * 2261) >> 16;          // u/29, exact for u<1102
                const int k4 = u - f * CHUNK_U16B;
                const uint4* src = T4 + (size_t)s_idx[f] * CHUNK_U16B + k4;
                __builtin_amdgcn_global_load_lds((gas_ptr)src, (las_ptr)(sM4 + u), 16, 0, 0);
            }
        }
    }
    __syncthreads();

    // pairwise term from LDS: 3 pairs per thread
    #pragma unroll
    for (int k = 0; k < 3; ++k) {
        int p = t + (k << 8);
        const bool valid = (p < NPAIRS);
        p = valid ? p : (NPAIRS - 1);
        int i, j;
        decode_pair(p, i, j);
        const float vv = s_val[i] * s_val[j] * INV_SCALE2;
        const unsigned* A = sM + j * CHUNK_U32 + 3 * i;   // emb[i, c_j], 10 fp8 in 3 dwords
        const unsigned* B = sM + i * CHUNK_U32 + 3 * j;   // emb[j, c_i]
        const unsigned a0 = A[0], a1 = A[1], a2 = A[2];
        const unsigned b0 = B[0], b1 = B[1], b2 = B[2];
        floatx2 s2;
        s2  = (floatx2)__builtin_amdgcn_cvt_pk_f32_fp8(a0, false) *
              (floatx2)__builtin_amdgcn_cvt_pk_f32_fp8(b0, false);
        s2 += (floatx2)__builtin_amdgcn_cvt_pk_f32_fp8(a0, true ) *
              (floatx2)__builtin_amdgcn_cvt_pk_f32_fp8(b0, true );
        s2 += (floatx2)__builtin_amdgcn_cvt_pk_f32_fp8(a1, false) *
              (floatx2)__builtin_amdgcn_cvt_pk_f32_fp8(b1, false);
        s2 += (floatx2)__builtin_amdgcn_cvt_pk_f32_fp8(a1, true ) *
              (floatx2)__builtin_amdgcn_cvt_pk_f32_fp8(b1, true );
        s2 += (floatx2)__builtin_amdgcn_cvt_pk_f32_fp8(a2, false) *
              (floatx2)__builtin_amdgcn_cvt_pk_f32_fp8(b2, false);
        const float s = s2.x + s2.y;
        acc += valid ? s * vv : 0.f;
    }

    // block reduction: wave64 shuffle, then 4 partials through LDS
    #pragma unroll
    for (int off = 32; off > 0; off >>= 1)
        acc += __shfl_down(acc, off, 64);

    __shared__ float wsum[4];
    if ((t & 63) == 0) wsum[t >> 6] = acc;
    __syncthreads();
    if (t == 0) {
        const float tot = wsum[0] + wsum[1] + wsum[2] + wsum[3];
        out[b] = 1.f / (1.f + expf(-tot));
    }
}

extern "C" void kernel_launch(void* const* d_in, const int* in_sizes, int n_in,
                              void* d_out, int out_size, void* d_ws, size_t ws_size,
                              hipStream_t stream) {
    const int*   idxs = (const int*)  d_in[0];   // [B, 39] int32
    const float* vals = (const float*)d_in[1];   // [B, 39] f32
    const float* emb  = (const float*)d_in[2];   // [39, 100000, 10] f32
    const float* w1   = (const float*)d_in[3];   // [100000, 1] f32
    float*       out  = (float*)d_out;           // [B] f32
    uint4*       T4   = (uint4*)d_ws;            // 100000 * 464 B = 46.4 MB
    unsigned char* flags = (unsigned char*)d_ws + FLAGS_OFF;  // 100 KB

    const int B    = out_size;
    const int nref = B * NPF;

    flag_kernel<<<(nref + 255) / 256, 256, 0, stream>>>(idxs, flags, nref);
    repack_kernel<<<FEAT / RCOLS, 256, 0, stream>>>((const float4*)emb, T4, flags);
    ffm_kernel<<<B, 256, 0, stream>>>(idxs, vals, T4, w1, out);
}